// Round 1
// baseline (1142.960 us; speedup 1.0000x reference)
//
#include <hip/hip_runtime.h>
#include <hip/hip_bf16.h>

#define NQ 20
#define NLAY 51            // N_LAYER+1
#define FEAT 128
#define BATCH 128
#define NN (BATCH * NQ * NLAY)   // 130560
#define NE 524288
#define NPAIR (BATCH * NQ * NQ)  // 51200

__device__ __forceinline__ float lrelu(float v) { return v >= 0.f ? v : 0.01f * v; }

// ---------------- embedding gather: h[r,:] = emb[x[r],:] ----------------
__global__ void k_embed(const int* __restrict__ x, const float* __restrict__ emb,
                        float* __restrict__ h) {
    int t = blockIdx.x * 256 + threadIdx.x;       // one float4 per thread
    int r = t >> 5, c4 = t & 31;
    int tok = x[r];
    ((float4*)(h + (size_t)r * FEAT))[c4] = ((const float4*)(emb + (size_t)tok * FEAT))[c4];
}

// ---------------- CSR build ----------------
__global__ void k_count(const int* __restrict__ dst, int* __restrict__ cnt) {
    int e = blockIdx.x * 256 + threadIdx.x;
    atomicAdd(&cnt[dst[e]], 1);
}

__global__ void k_partial(const int* __restrict__ cnt, int* __restrict__ part) {
    __shared__ int sm[256];
    int t = threadIdx.x;
    sm[t] = cnt[blockIdx.x * 256 + t];
    __syncthreads();
    for (int s = 128; s > 0; s >>= 1) {
        if (t < s) sm[t] += sm[t + s];
        __syncthreads();
    }
    if (t == 0) part[blockIdx.x] = sm[0];
}

__global__ void k_scanpart(const int* __restrict__ part, int* __restrict__ pscan, int nb) {
    __shared__ int sm[512];
    int t = threadIdx.x;
    int v = (t < nb) ? part[t] : 0;
    sm[t] = v;
    __syncthreads();
    for (int s = 1; s < 512; s <<= 1) {
        int add = (t >= s) ? sm[t - s] : 0;
        __syncthreads();
        sm[t] += add;
        __syncthreads();
    }
    if (t < nb) pscan[t] = sm[t] - v;   // exclusive
}

__global__ void k_offsets(const int* __restrict__ cnt, const int* __restrict__ pscan,
                          int* __restrict__ offs) {
    __shared__ int sm[256];
    int t = threadIdx.x, g = blockIdx.x * 256 + t;
    int v = cnt[g];
    sm[t] = v;
    __syncthreads();
    for (int s = 1; s < 256; s <<= 1) {
        int add = (t >= s) ? sm[t - s] : 0;
        __syncthreads();
        sm[t] += add;
        __syncthreads();
    }
    offs[g] = pscan[blockIdx.x] + sm[t] - v;
}

__global__ void k_fill(const int* __restrict__ src, const int* __restrict__ dst,
                       const int* __restrict__ offs, int* __restrict__ fill,
                       int* __restrict__ csr) {
    int e = blockIdx.x * 256 + threadIdx.x;
    int d = dst[e];
    int pos = offs[d] + atomicAdd(&fill[d], 1);
    csr[pos] = src[e];
}

__global__ void k_dinv(const int* __restrict__ cnt, float* __restrict__ dinv) {
    int g = blockIdx.x * 256 + threadIdx.x;
    dinv[g] = rsqrtf((float)(cnt[g] + 1));  // +1 self loop
}

// ---------------- classic fp32 SGEMM, C = A(MxK) * B(KxN) [+bias][leaky] ----------------
template <int BM, int BN, int BK, int TM, int TN, bool LEAKY, bool BIAS>
__launch_bounds__((BM / TM) * (BN / TN))
__global__ void sgemm(const float* __restrict__ A, const float* __restrict__ Bm,
                      const float* __restrict__ bias, float* __restrict__ C,
                      int M, int N, int K) {
    constexpr int NT = (BM / TM) * (BN / TN);
    __shared__ float As[BK][BM];
    __shared__ float Bs[BK][BN];
    const int tid = threadIdx.x;
    const int bx = blockIdx.x, by = blockIdx.y;
    const int tcol = tid % (BN / TN);
    const int trow = tid / (BN / TN);
    const float* Ablk = A + (size_t)by * BM * K;
    const float* Bblk = Bm + (size_t)bx * BN;

    float acc[TM][TN];
#pragma unroll
    for (int i = 0; i < TM; i++)
#pragma unroll
        for (int j = 0; j < TN; j++) acc[i][j] = 0.f;

    for (int k0 = 0; k0 < K; k0 += BK) {
#pragma unroll 2
        for (int idx = tid; idx < BM * BK / 4; idx += NT) {
            int row = idx / (BK / 4);
            int c4 = idx % (BK / 4);
            float4 v = *(const float4*)(Ablk + (size_t)row * K + k0 + c4 * 4);
            As[c4 * 4 + 0][row] = v.x;
            As[c4 * 4 + 1][row] = v.y;
            As[c4 * 4 + 2][row] = v.z;
            As[c4 * 4 + 3][row] = v.w;
        }
#pragma unroll 2
        for (int idx = tid; idx < BK * BN / 4; idx += NT) {
            int row = idx / (BN / 4);
            int c4 = idx % (BN / 4);
            *(float4*)(&Bs[row][c4 * 4]) = *(const float4*)(Bblk + (size_t)(k0 + row) * N + c4 * 4);
        }
        __syncthreads();
#pragma unroll
        for (int k = 0; k < BK; k++) {
            float af[TM], bf[TN];
#pragma unroll
            for (int i = 0; i < TM; i += 4) *(float4*)(&af[i]) = *(const float4*)(&As[k][trow * TM + i]);
#pragma unroll
            for (int j = 0; j < TN; j += 4) *(float4*)(&bf[j]) = *(const float4*)(&Bs[k][tcol * TN + j]);
#pragma unroll
            for (int i = 0; i < TM; i++)
#pragma unroll
                for (int j = 0; j < TN; j++) acc[i][j] += af[i] * bf[j];
        }
        __syncthreads();
    }

#pragma unroll
    for (int i = 0; i < TM; i++) {
        int r = by * BM + trow * TM + i;
#pragma unroll
        for (int j = 0; j < TN; j += 4) {
            float4 v;
            float* pv = &v.x;
#pragma unroll
            for (int q = 0; q < 4; q++) {
                float val = acc[i][j + q];
                if (BIAS) val += bias[bx * BN + tcol * TN + j + q];
                if (LEAKY) val = lrelu(val);
                pv[q] = val;
            }
            *(float4*)(C + (size_t)r * N + bx * BN + tcol * TN + j) = v;
        }
    }
}

// ---------------- GCN aggregation + bias + (leaky) + residual ----------------
// one wave per node, lane covers 2 feats
__global__ void k_agg(const float* __restrict__ hw, const float* __restrict__ hold,
                      const int* __restrict__ csr, const int* __restrict__ offs,
                      const int* __restrict__ cnt, const float* __restrict__ dinv,
                      const float* __restrict__ bias, float* __restrict__ hnew,
                      int leaky) {
    int wave = threadIdx.x >> 6;
    int lane = threadIdx.x & 63;
    int node = blockIdx.x * 4 + wave;
    float di = dinv[node];
    float2 v = ((const float2*)(hw + (size_t)node * FEAT))[lane];
    float accx = v.x * di * di, accy = v.y * di * di;
    int off = offs[node], c = cnt[node];
    for (int e = 0; e < c; e++) {
        int s = csr[off + e];
        float ns = dinv[s] * di;
        float2 u = ((const float2*)(hw + (size_t)s * FEAT))[lane];
        accx += u.x * ns;
        accy += u.y * ns;
    }
    float ox = accx + bias[lane * 2];
    float oy = accy + bias[lane * 2 + 1];
    if (leaky) { ox = lrelu(ox); oy = lrelu(oy); }
    float2 ho = ((const float2*)(hold + (size_t)node * FEAT))[lane];
    ((float2*)(hnew + (size_t)node * FEAT))[lane] = make_float2(ox + ho.x, oy + ho.y);
}

// ---------------- extract first-20 nodes per graph ----------------
__global__ void k_hq(const float* __restrict__ h, float* __restrict__ hq) {
    int t = blockIdx.x * 256 + threadIdx.x;  // 2560*32 float4
    int r = t >> 5, c4 = t & 31;
    int b = r / NQ, q = r % NQ;
    ((float4*)(hq + (size_t)r * FEAT))[c4] =
        ((const float4*)(h + (size_t)(b * NQ * NLAY + q) * FEAT))[c4];
}

// ---------------- pair layer-0: X0[p] = leaky(A[b,i] + B[b,j] + mb0) ----------------
__global__ void k_pair0(const float* __restrict__ Ab, const float* __restrict__ Bb,
                        const float* __restrict__ mb0, float* __restrict__ X0) {
    int t = blockIdx.x * 256 + threadIdx.x;  // 51200*64 float4
    int p = t >> 6, c4 = t & 63;
    int b = p / (NQ * NQ), r = p % (NQ * NQ);
    int i = r / NQ, j = r % NQ;
    float4 a = ((const float4*)(Ab + (size_t)(b * NQ + i) * 256))[c4];
    float4 bb = ((const float4*)(Bb + (size_t)(b * NQ + j) * 256))[c4];
    float4 m = ((const float4*)mb0)[c4];
    float4 o;
    o.x = lrelu(a.x + bb.x + m.x);
    o.y = lrelu(a.y + bb.y + m.y);
    o.z = lrelu(a.z + bb.z + m.z);
    o.w = lrelu(a.w + bb.w + m.w);
    ((float4*)(X0 + (size_t)p * 256))[c4] = o;
}

// ---------------- last layer: P[p] = X4[p,:] . mw5 + mb5 ----------------
__global__ void k_last(const float* __restrict__ X4, const float* __restrict__ mw5,
                       const float* __restrict__ mb5, float* __restrict__ P) {
    __shared__ float w[64];
    if (threadIdx.x < 64) w[threadIdx.x] = mw5[threadIdx.x];
    __syncthreads();
    int p = blockIdx.x * 256 + threadIdx.x;
    const float4* row = (const float4*)(X4 + (size_t)p * 64);
    float s = 0.f;
#pragma unroll
    for (int k4 = 0; k4 < 16; k4++) {
        float4 v = row[k4];
        s += v.x * w[k4 * 4] + v.y * w[k4 * 4 + 1] + v.z * w[k4 * 4 + 2] + v.w * w[k4 * 4 + 3];
    }
    P[p] = s + mb5[0];
}

// ---------------- symmetrize ----------------
__global__ void k_sym(const float* __restrict__ P, float* __restrict__ out) {
    int p = blockIdx.x * 256 + threadIdx.x;
    int b = p / (NQ * NQ), r = p % (NQ * NQ);
    int i = r / NQ, j = r % NQ;
    out[p] = 0.5f * (P[p] + P[b * NQ * NQ + j * NQ + i]);
}

extern "C" void kernel_launch(void* const* d_in, const int* in_sizes, int n_in,
                              void* d_out, int out_size, void* d_ws, size_t ws_size,
                              hipStream_t stream) {
    const int* x = (const int*)d_in[0];
    const int* ei = (const int*)d_in[1];
    const int* e_src = ei;
    const int* e_dst = ei + NE;
    const float* emb = (const float*)d_in[2];
    const float* gw = (const float*)d_in[3];   // [5,128,128]
    const float* gb = (const float*)d_in[4];   // [5,128]
    const float* mw0 = (const float*)d_in[5];
    const float* mb0 = (const float*)d_in[6];
    const float* mw1 = (const float*)d_in[7];
    const float* mb1 = (const float*)d_in[8];
    const float* mw2 = (const float*)d_in[9];
    const float* mb2 = (const float*)d_in[10];
    const float* mw3 = (const float*)d_in[11];
    const float* mb3 = (const float*)d_in[12];
    const float* mw4 = (const float*)d_in[13];
    const float* mb4 = (const float*)d_in[14];
    const float* mw5 = (const float*)d_in[15];
    const float* mb5 = (const float*)d_in[16];
    float* out = (float*)d_out;

    float* wsf = (float*)d_ws;
    size_t o = 0;
    const size_t HSZ = (size_t)NN * FEAT;             // 16,711,680
    float* hA = wsf + o; o += HSZ;
    float* hw = wsf + o; o += HSZ;
    float* hB = wsf + o; o += HSZ;
    int* cnt  = (int*)(wsf + o); o += NN;
    int* fill = (int*)(wsf + o); o += NN;
    int* offs = (int*)(wsf + o); o += NN;
    int* csr  = (int*)(wsf + o); o += NE;
    float* dinv = wsf + o; o += NN;
    int* part  = (int*)(wsf + o); o += 512;
    int* pscan = (int*)(wsf + o); o += 512;
    float* hq = wsf + o; o += (size_t)BATCH * NQ * FEAT;     // 327,680
    float* Abuf = wsf + o; o += (size_t)BATCH * NQ * 256;    // 655,360
    float* Bbuf = wsf + o; o += (size_t)BATCH * NQ * 256;    // 655,360
    float* P = wsf + o; o += NPAIR;
    // aliases into freed h buffers (pair phase only)
    float* X0 = hA;                        // 51200*256
    float* X1 = hw;                        // 51200*128
    float* X2 = hw + (size_t)NPAIR * 128;  // 51200*128
    float* X3 = hB;                        // 51200*64
    float* X4 = hB + (size_t)NPAIR * 64;   // 51200*64

    const int NB = NN / 256;  // 510

    // --- CSR build ---
    hipMemsetAsync(cnt, 0, NN * sizeof(int), stream);
    hipMemsetAsync(fill, 0, NN * sizeof(int), stream);
    k_count<<<NE / 256, 256, 0, stream>>>(e_dst, cnt);
    k_partial<<<NB, 256, 0, stream>>>(cnt, part);
    k_scanpart<<<1, 512, 0, stream>>>(part, pscan, NB);
    k_offsets<<<NB, 256, 0, stream>>>(cnt, pscan, offs);
    k_fill<<<NE / 256, 256, 0, stream>>>(e_src, e_dst, offs, fill, csr);
    k_dinv<<<NB, 256, 0, stream>>>(cnt, dinv);

    // --- embedding ---
    k_embed<<<(NN * 32) / 256, 256, 0, stream>>>(x, emb, hA);

    // --- 5 GCN layers, ping-pong hA/hB ---
    float* hin = hA;
    float* hout = hB;
    for (int L = 0; L < 5; L++) {
        sgemm<128, 128, 8, 8, 8, false, false><<<dim3(1, NN / 128), 256, 0, stream>>>(
            hin, gw + (size_t)L * FEAT * FEAT, nullptr, hw, NN, FEAT, FEAT);
        k_agg<<<NN / 4, 256, 0, stream>>>(hw, hin, csr, offs, cnt, dinv,
                                          gb + (size_t)L * FEAT, hout, L < 4 ? 1 : 0);
        float* t = hin; hin = hout; hout = t;
    }
    // final h is in hin (== hB after 5 swaps)

    // --- pair MLP ---
    k_hq<<<(BATCH * NQ * 32) / 256, 256, 0, stream>>>(hin, hq);
    // A = hq @ mw0[:128,:], B = hq @ mw0[128:,:]   (M=2560, K=128, N=256)
    sgemm<128, 128, 8, 8, 8, false, false><<<dim3(2, 20), 256, 0, stream>>>(
        hq, mw0, nullptr, Abuf, BATCH * NQ, 256, 128);
    sgemm<128, 128, 8, 8, 8, false, false><<<dim3(2, 20), 256, 0, stream>>>(
        hq, mw0 + 128 * 256, nullptr, Bbuf, BATCH * NQ, 256, 128);
    k_pair0<<<(NPAIR * 64) / 256, 256, 0, stream>>>(Abuf, Bbuf, mb0, X0);
    // L1: [51200,256] @ [256,128]
    sgemm<128, 128, 8, 8, 8, true, true><<<dim3(1, NPAIR / 128), 256, 0, stream>>>(
        X0, mw1, mb1, X1, NPAIR, 128, 256);
    // L2: [51200,128] @ [128,128]
    sgemm<128, 128, 8, 8, 8, true, true><<<dim3(1, NPAIR / 128), 256, 0, stream>>>(
        X1, mw2, mb2, X2, NPAIR, 128, 128);
    // L3: [51200,128] @ [128,64]
    sgemm<128, 64, 8, 8, 4, true, true><<<dim3(1, NPAIR / 128), 256, 0, stream>>>(
        X2, mw3, mb3, X3, NPAIR, 64, 128);
    // L4: [51200,64] @ [64,64]
    sgemm<128, 64, 8, 8, 4, true, true><<<dim3(1, NPAIR / 128), 256, 0, stream>>>(
        X3, mw4, mb4, X4, NPAIR, 64, 64);
    // L5 + symmetrize
    k_last<<<NPAIR / 256, 256, 0, stream>>>(X4, mw5, mb5, P);
    k_sym<<<NPAIR / 256, 256, 0, stream>>>(P, out);
}

// Round 2
// 860.435 us; speedup vs baseline: 1.3284x; 1.3284x over previous
//
#include <hip/hip_runtime.h>
#include <hip/hip_bf16.h>

#define NQ 20
#define NLAY 51            // N_LAYER+1
#define FEAT 128
#define BATCH 128
#define NN (BATCH * NQ * NLAY)   // 130560
#define NE 524288
#define NPAIR (BATCH * NQ * NQ)  // 51200

typedef _Float16 half8 __attribute__((ext_vector_type(8)));
typedef float floatx4 __attribute__((ext_vector_type(4)));

__device__ __forceinline__ float lrelu(float v) { return v >= 0.f ? v : 0.01f * v; }

// ---------------- embedding gather: h[r,:] = emb[x[r],:] ----------------
__global__ void k_embed(const int* __restrict__ x, const float* __restrict__ emb,
                        float* __restrict__ h) {
    int t = blockIdx.x * 256 + threadIdx.x;       // one float4 per thread
    int r = t >> 5, c4 = t & 31;
    int tok = x[r];
    ((float4*)(h + (size_t)r * FEAT))[c4] = ((const float4*)(emb + (size_t)tok * FEAT))[c4];
}

// ---------------- CSR build ----------------
__global__ void k_count(const int* __restrict__ dst, int* __restrict__ cnt) {
    int e = blockIdx.x * 256 + threadIdx.x;
    atomicAdd(&cnt[dst[e]], 1);
}

__global__ void k_partial(const int* __restrict__ cnt, int* __restrict__ part) {
    __shared__ int sm[256];
    int t = threadIdx.x;
    sm[t] = cnt[blockIdx.x * 256 + t];
    __syncthreads();
    for (int s = 128; s > 0; s >>= 1) {
        if (t < s) sm[t] += sm[t + s];
        __syncthreads();
    }
    if (t == 0) part[blockIdx.x] = sm[0];
}

__global__ void k_scanpart(const int* __restrict__ part, int* __restrict__ pscan, int nb) {
    __shared__ int sm[512];
    int t = threadIdx.x;
    int v = (t < nb) ? part[t] : 0;
    sm[t] = v;
    __syncthreads();
    for (int s = 1; s < 512; s <<= 1) {
        int add = (t >= s) ? sm[t - s] : 0;
        __syncthreads();
        sm[t] += add;
        __syncthreads();
    }
    if (t < nb) pscan[t] = sm[t] - v;   // exclusive
}

__global__ void k_offsets(const int* __restrict__ cnt, const int* __restrict__ pscan,
                          int* __restrict__ offs) {
    __shared__ int sm[256];
    int t = threadIdx.x, g = blockIdx.x * 256 + t;
    int v = cnt[g];
    sm[t] = v;
    __syncthreads();
    for (int s = 1; s < 256; s <<= 1) {
        int add = (t >= s) ? sm[t - s] : 0;
        __syncthreads();
        sm[t] += add;
        __syncthreads();
    }
    offs[g] = pscan[blockIdx.x] + sm[t] - v;
}

__global__ void k_dinv(const int* __restrict__ cnt, float* __restrict__ dinv) {
    int g = blockIdx.x * 256 + threadIdx.x;
    dinv[g] = rsqrtf((float)(cnt[g] + 1));  // +1 self loop
}

// fill CSR; also store dinv[src] per slot so agg avoids the random dinv gather
__global__ void k_fill(const int* __restrict__ src, const int* __restrict__ dst,
                       const int* __restrict__ offs, int* __restrict__ fill,
                       const float* __restrict__ dinv,
                       int* __restrict__ csr, float* __restrict__ csrw) {
    int e = blockIdx.x * 256 + threadIdx.x;
    int d = dst[e];
    int s = src[e];
    int pos = offs[d] + atomicAdd(&fill[d], 1);
    csr[pos] = s;
    csrw[pos] = dinv[s];
}

// ---------------- weight transpose + fp16 hi/lo split (once per launch) ----------------
// layout offsets in halves within bt_hi / bt_lo
#define OFF_GCN 0                 // 5 x [128][128] K=128 N=128
#define OFF_P0A 81920             // mw0 top:    K=128 N=256
#define OFF_P0B 114688            // mw0 bottom: K=128 N=256
#define OFF_M1  147456            // mw1: K=256 N=128
#define OFF_M2  180224            // mw2: K=128 N=128
#define OFF_M3  196608            // mw3: K=128 N=64
#define OFF_M4  204800            // mw4: K=64  N=64
#define TS_TOTAL 208896

__global__ void k_tsplit_all(const float* __restrict__ gw, const float* __restrict__ mw0,
                             const float* __restrict__ mw1, const float* __restrict__ mw2,
                             const float* __restrict__ mw3, const float* __restrict__ mw4,
                             _Float16* __restrict__ hi, _Float16* __restrict__ lo) {
    int idx = blockIdx.x * 256 + threadIdx.x;
    const float* src;
    int K, N, base, rel;
    if (idx < OFF_P0A) {
        int L = idx >> 14; rel = idx & 16383;
        src = gw + L * 16384; K = 128; N = 128; base = OFF_GCN + L * 16384;
    } else if (idx < OFF_P0B) {
        rel = idx - OFF_P0A; src = mw0;             K = 128; N = 256; base = OFF_P0A;
    } else if (idx < OFF_M1) {
        rel = idx - OFF_P0B; src = mw0 + 128 * 256; K = 128; N = 256; base = OFF_P0B;
    } else if (idx < OFF_M2) {
        rel = idx - OFF_M1;  src = mw1;             K = 256; N = 128; base = OFF_M1;
    } else if (idx < OFF_M3) {
        rel = idx - OFF_M2;  src = mw2;             K = 128; N = 128; base = OFF_M2;
    } else if (idx < OFF_M4) {
        rel = idx - OFF_M3;  src = mw3;             K = 128; N = 64;  base = OFF_M3;
    } else {
        rel = idx - OFF_M4;  src = mw4;             K = 64;  N = 64;  base = OFF_M4;
    }
    int k = rel / N, n = rel % N;
    float f = src[k * N + n];
    _Float16 h = (_Float16)f;
    hi[base + n * K + k] = h;
    lo[base + n * K + k] = (_Float16)(f - (float)h);
}

// ---------------- split-fp16 MFMA GEMM: C = A(fp32 MxK) * B(KxN) [+bias][leaky] ----------
// B given pre-transposed+split: Bt[n][k] in f16 hi/lo. 3-product Markidis split
// (hi*hi + hi*lo + lo*hi), fp32 accumulate -> ~fp32 accuracy.
// Block = 256 thr = 4 waves; wave owns 32 rows (2 m-tiles) x NT_N*16 cols. No LDS.
template <int NT_N, bool LEAKY, bool BIAS>
__launch_bounds__(256, 2)
__global__ void hgemm(const float* __restrict__ A, const _Float16* __restrict__ Bth,
                      const _Float16* __restrict__ Btl, const float* __restrict__ bias,
                      float* __restrict__ C, int N, int K) {
    const int lane = threadIdx.x & 63;
    const int wid = threadIdx.x >> 6;
    const int lm = lane & 15, lq = lane >> 4;
    const int m0 = blockIdx.x * 128 + wid * 32;
    const int n0 = blockIdx.y * (NT_N * 16);

    floatx4 acc[2][NT_N];
#pragma unroll
    for (int mt = 0; mt < 2; mt++)
#pragma unroll
        for (int nt = 0; nt < NT_N; nt++) acc[mt][nt] = (floatx4)0.f;

    for (int k0 = 0; k0 < K; k0 += 32) {
        half8 ahi[2], alo[2];
#pragma unroll
        for (int mt = 0; mt < 2; mt++) {
            const float* ap = A + (size_t)(m0 + mt * 16 + lm) * K + k0 + lq * 8;
            floatx4 av0 = *(const floatx4*)ap;
            floatx4 av1 = *(const floatx4*)(ap + 4);
#pragma unroll
            for (int j = 0; j < 4; j++) {
                _Float16 h0 = (_Float16)av0[j];
                ahi[mt][j] = h0;
                alo[mt][j] = (_Float16)(av0[j] - (float)h0);
                _Float16 h1 = (_Float16)av1[j];
                ahi[mt][4 + j] = h1;
                alo[mt][4 + j] = (_Float16)(av1[j] - (float)h1);
            }
        }
#pragma unroll
        for (int nt = 0; nt < NT_N; nt++) {
            size_t boff = (size_t)(n0 + nt * 16 + lm) * K + k0 + lq * 8;
            half8 bhi = *(const half8*)(Bth + boff);
            half8 blo = *(const half8*)(Btl + boff);
#pragma unroll
            for (int mt = 0; mt < 2; mt++) {
                acc[mt][nt] = __builtin_amdgcn_mfma_f32_16x16x32_f16(ahi[mt], bhi, acc[mt][nt], 0, 0, 0);
                acc[mt][nt] = __builtin_amdgcn_mfma_f32_16x16x32_f16(ahi[mt], blo, acc[mt][nt], 0, 0, 0);
                acc[mt][nt] = __builtin_amdgcn_mfma_f32_16x16x32_f16(alo[mt], bhi, acc[mt][nt], 0, 0, 0);
            }
        }
    }

    // epilogue: C/D layout col=lane&15, row=(lane>>4)*4+reg
#pragma unroll
    for (int nt = 0; nt < NT_N; nt++) {
        int col = n0 + nt * 16 + lm;
        float bv = BIAS ? bias[col] : 0.f;
#pragma unroll
        for (int mt = 0; mt < 2; mt++) {
#pragma unroll
            for (int r = 0; r < 4; r++) {
                int row = m0 + mt * 16 + lq * 4 + r;
                float val = acc[mt][nt][r] + bv;
                if (LEAKY) val = lrelu(val);
                C[(size_t)row * N + col] = val;
            }
        }
    }
}

// ---------------- GCN aggregation + bias + (leaky) + residual ----------------
// one wave per node, lane covers 2 feats; 4-deep edge unroll for MLP
__global__ void k_agg(const float* __restrict__ hw, const float* __restrict__ hold,
                      const int* __restrict__ csr, const float* __restrict__ csrw,
                      const int* __restrict__ offs, const int* __restrict__ cnt,
                      const float* __restrict__ dinv, const float* __restrict__ bias,
                      float* __restrict__ hnew, int leaky) {
    int wave = threadIdx.x >> 6;
    int lane = threadIdx.x & 63;
    int node = __builtin_amdgcn_readfirstlane(blockIdx.x * 4 + wave);
    float di = dinv[node];
    float2 v = ((const float2*)(hw + (size_t)node * FEAT))[lane];
    float accx = v.x * di * di, accy = v.y * di * di;
    int off = offs[node], c = cnt[node];
    int e = 0;
    for (; e + 4 <= c; e += 4) {
        int s0 = csr[off + e], s1 = csr[off + e + 1], s2 = csr[off + e + 2], s3 = csr[off + e + 3];
        float w0 = csrw[off + e] * di, w1 = csrw[off + e + 1] * di;
        float w2 = csrw[off + e + 2] * di, w3 = csrw[off + e + 3] * di;
        float2 u0 = ((const float2*)(hw + (size_t)s0 * FEAT))[lane];
        float2 u1 = ((const float2*)(hw + (size_t)s1 * FEAT))[lane];
        float2 u2 = ((const float2*)(hw + (size_t)s2 * FEAT))[lane];
        float2 u3 = ((const float2*)(hw + (size_t)s3 * FEAT))[lane];
        accx += u0.x * w0 + u1.x * w1 + u2.x * w2 + u3.x * w3;
        accy += u0.y * w0 + u1.y * w1 + u2.y * w2 + u3.y * w3;
    }
    for (; e < c; e++) {
        int s = csr[off + e];
        float ns = csrw[off + e] * di;
        float2 u = ((const float2*)(hw + (size_t)s * FEAT))[lane];
        accx += u.x * ns;
        accy += u.y * ns;
    }
    float ox = accx + bias[lane * 2];
    float oy = accy + bias[lane * 2 + 1];
    if (leaky) { ox = lrelu(ox); oy = lrelu(oy); }
    float2 ho = ((const float2*)(hold + (size_t)node * FEAT))[lane];
    ((float2*)(hnew + (size_t)node * FEAT))[lane] = make_float2(ox + ho.x, oy + ho.y);
}

// ---------------- extract first-20 nodes per graph ----------------
__global__ void k_hq(const float* __restrict__ h, float* __restrict__ hq) {
    int t = blockIdx.x * 256 + threadIdx.x;  // 2560*32 float4
    int r = t >> 5, c4 = t & 31;
    int b = r / NQ, q = r % NQ;
    ((float4*)(hq + (size_t)r * FEAT))[c4] =
        ((const float4*)(h + (size_t)(b * NQ * NLAY + q) * FEAT))[c4];
}

// ---------------- pair layer-0: X0[p] = leaky(A[b,i] + B[b,j] + mb0) ----------------
__global__ void k_pair0(const float* __restrict__ Ab, const float* __restrict__ Bb,
                        const float* __restrict__ mb0, float* __restrict__ X0) {
    int t = blockIdx.x * 256 + threadIdx.x;  // 51200*64 float4
    int p = t >> 6, c4 = t & 63;
    int b = p / (NQ * NQ), r = p % (NQ * NQ);
    int i = r / NQ, j = r % NQ;
    float4 a = ((const float4*)(Ab + (size_t)(b * NQ + i) * 256))[c4];
    float4 bb = ((const float4*)(Bb + (size_t)(b * NQ + j) * 256))[c4];
    float4 m = ((const float4*)mb0)[c4];
    float4 o;
    o.x = lrelu(a.x + bb.x + m.x);
    o.y = lrelu(a.y + bb.y + m.y);
    o.z = lrelu(a.z + bb.z + m.z);
    o.w = lrelu(a.w + bb.w + m.w);
    ((float4*)(X0 + (size_t)p * 256))[c4] = o;
}

// ---------------- last layer: P[p] = X4[p,:] . mw5 + mb5 ----------------
__global__ void k_last(const float* __restrict__ X4, const float* __restrict__ mw5,
                       const float* __restrict__ mb5, float* __restrict__ P) {
    __shared__ float w[64];
    if (threadIdx.x < 64) w[threadIdx.x] = mw5[threadIdx.x];
    __syncthreads();
    int p = blockIdx.x * 256 + threadIdx.x;
    const float4* row = (const float4*)(X4 + (size_t)p * 64);
    float s = 0.f;
#pragma unroll
    for (int k4 = 0; k4 < 16; k4++) {
        float4 v = row[k4];
        s += v.x * w[k4 * 4] + v.y * w[k4 * 4 + 1] + v.z * w[k4 * 4 + 2] + v.w * w[k4 * 4 + 3];
    }
    P[p] = s + mb5[0];
}

// ---------------- symmetrize ----------------
__global__ void k_sym(const float* __restrict__ P, float* __restrict__ out) {
    int p = blockIdx.x * 256 + threadIdx.x;
    int b = p / (NQ * NQ), r = p % (NQ * NQ);
    int i = r / NQ, j = r % NQ;
    out[p] = 0.5f * (P[p] + P[b * NQ * NQ + j * NQ + i]);
}

extern "C" void kernel_launch(void* const* d_in, const int* in_sizes, int n_in,
                              void* d_out, int out_size, void* d_ws, size_t ws_size,
                              hipStream_t stream) {
    const int* x = (const int*)d_in[0];
    const int* ei = (const int*)d_in[1];
    const int* e_src = ei;
    const int* e_dst = ei + NE;
    const float* emb = (const float*)d_in[2];
    const float* gw = (const float*)d_in[3];   // [5,128,128]
    const float* gb = (const float*)d_in[4];   // [5,128]
    const float* mw0 = (const float*)d_in[5];
    const float* mb0 = (const float*)d_in[6];
    const float* mw1 = (const float*)d_in[7];
    const float* mb1 = (const float*)d_in[8];
    const float* mw2 = (const float*)d_in[9];
    const float* mb2 = (const float*)d_in[10];
    const float* mw3 = (const float*)d_in[11];
    const float* mb3 = (const float*)d_in[12];
    const float* mw4 = (const float*)d_in[13];
    const float* mb4 = (const float*)d_in[14];
    const float* mw5 = (const float*)d_in[15];
    const float* mb5 = (const float*)d_in[16];
    float* out = (float*)d_out;

    float* wsf = (float*)d_ws;
    size_t o = 0;
    const size_t HSZ = (size_t)NN * FEAT;             // 16,711,680
    float* hA = wsf + o; o += HSZ;
    float* hw = wsf + o; o += HSZ;
    float* hB = wsf + o; o += HSZ;
    int* cnt  = (int*)(wsf + o); o += NN;
    int* fill = (int*)(wsf + o); o += NN;
    int* offs = (int*)(wsf + o); o += NN;
    int* csr  = (int*)(wsf + o); o += NE;
    float* csrw = wsf + o; o += NE;
    float* dinv = wsf + o; o += NN;
    int* part  = (int*)(wsf + o); o += 512;
    int* pscan = (int*)(wsf + o); o += 512;
    float* hq = wsf + o; o += (size_t)BATCH * NQ * FEAT;     // 327,680
    float* Abuf = wsf + o; o += (size_t)BATCH * NQ * 256;    // 655,360
    float* Bbuf = wsf + o; o += (size_t)BATCH * NQ * 256;    // 655,360
    float* P = wsf + o; o += NPAIR;
    _Float16* bt_hi = (_Float16*)(wsf + o); o += (TS_TOTAL + 2) / 2;
    _Float16* bt_lo = (_Float16*)(wsf + o); o += (TS_TOTAL + 2) / 2;
    // aliases into freed h buffers (pair phase only)
    float* X0 = hA;                        // 51200*256
    float* X1 = hw;                        // 51200*128
    float* X2 = hw + (size_t)NPAIR * 128;  // 51200*128
    float* X3 = hB;                        // 51200*64
    float* X4 = hB + (size_t)NPAIR * 64;   // 51200*64

    const int NB = NN / 256;  // 510

    // --- weight transpose+split (independent of everything else) ---
    k_tsplit_all<<<TS_TOTAL / 256, 256, 0, stream>>>(gw, mw0, mw1, mw2, mw3, mw4, bt_hi, bt_lo);

    // --- CSR build ---
    hipMemsetAsync(cnt, 0, NN * sizeof(int), stream);
    hipMemsetAsync(fill, 0, NN * sizeof(int), stream);
    k_count<<<NE / 256, 256, 0, stream>>>(e_dst, cnt);
    k_partial<<<NB, 256, 0, stream>>>(cnt, part);
    k_scanpart<<<1, 512, 0, stream>>>(part, pscan, NB);
    k_offsets<<<NB, 256, 0, stream>>>(cnt, pscan, offs);
    k_dinv<<<NB, 256, 0, stream>>>(cnt, dinv);
    k_fill<<<NE / 256, 256, 0, stream>>>(e_src, e_dst, offs, fill, dinv, csr, csrw);

    // --- embedding ---
    k_embed<<<(NN * 32) / 256, 256, 0, stream>>>(x, emb, hA);

    // --- 5 GCN layers, ping-pong hA/hB ---
    float* hin = hA;
    float* hout = hB;
    for (int L = 0; L < 5; L++) {
        hgemm<8, false, false><<<dim3(NN / 128, 1), 256, 0, stream>>>(
            hin, bt_hi + OFF_GCN + L * 16384, bt_lo + OFF_GCN + L * 16384, nullptr, hw, FEAT, FEAT);
        k_agg<<<NN / 4, 256, 0, stream>>>(hw, hin, csr, csrw, offs, cnt, dinv,
                                          gb + (size_t)L * FEAT, hout, L < 4 ? 1 : 0);
        float* t = hin; hin = hout; hout = t;
    }

    // --- pair MLP ---
    k_hq<<<(BATCH * NQ * 32) / 256, 256, 0, stream>>>(hin, hq);
    // A = hq @ mw0[:128,:], B = hq @ mw0[128:,:]   (M=2560, K=128, N=256)
    hgemm<8, false, false><<<dim3(20, 2), 256, 0, stream>>>(
        hq, bt_hi + OFF_P0A, bt_lo + OFF_P0A, nullptr, Abuf, 256, 128);
    hgemm<8, false, false><<<dim3(20, 2), 256, 0, stream>>>(
        hq, bt_hi + OFF_P0B, bt_lo + OFF_P0B, nullptr, Bbuf, 256, 128);
    k_pair0<<<(NPAIR * 64) / 256, 256, 0, stream>>>(Abuf, Bbuf, mb0, X0);
    // L1: [51200,256] @ [256,128]
    hgemm<8, true, true><<<dim3(NPAIR / 128, 1), 256, 0, stream>>>(
        X0, bt_hi + OFF_M1, bt_lo + OFF_M1, mb1, X1, 128, 256);
    // L2: [51200,128] @ [128,128]
    hgemm<8, true, true><<<dim3(NPAIR / 128, 1), 256, 0, stream>>>(
        X1, bt_hi + OFF_M2, bt_lo + OFF_M2, mb2, X2, 128, 128);
    // L3: [51200,128] @ [128,64]
    hgemm<4, true, true><<<dim3(NPAIR / 128, 1), 256, 0, stream>>>(
        X2, bt_hi + OFF_M3, bt_lo + OFF_M3, mb3, X3, 64, 128);
    // L4: [51200,64] @ [64,64]
    hgemm<4, true, true><<<dim3(NPAIR / 128, 1), 256, 0, stream>>>(
        X3, bt_hi + OFF_M4, bt_lo + OFF_M4, mb4, X4, 64, 64);
    // L5 + symmetrize
    k_last<<<NPAIR / 256, 256, 0, stream>>>(X4, mw5, mb5, P);
    k_sym<<<NPAIR / 256, 256, 0, stream>>>(P, out);
}

// Round 3
// 729.237 us; speedup vs baseline: 1.5673x; 1.1799x over previous
//
#include <hip/hip_runtime.h>
#include <hip/hip_bf16.h>

#define NQ 20
#define NLAY 51            // N_LAYER+1
#define FEAT 128
#define BATCH 128
#define NN (BATCH * NQ * NLAY)   // 130560
#define NE 524288
#define NPAIR (BATCH * NQ * NQ)  // 51200

typedef _Float16 half8 __attribute__((ext_vector_type(8)));
typedef float floatx4 __attribute__((ext_vector_type(4)));

__device__ __forceinline__ float lrelu(float v) { return v >= 0.f ? v : 0.01f * v; }

// ---------------- embedding gather ----------------
__global__ void k_embed(const int* __restrict__ x, const float* __restrict__ emb,
                        float* __restrict__ h) {
    int t = blockIdx.x * 256 + threadIdx.x;
    int r = t >> 5, c4 = t & 31;
    int tok = x[r];
    ((float4*)(h + (size_t)r * FEAT))[c4] = ((const float4*)(emb + (size_t)tok * FEAT))[c4];
}

// ---------------- CSR build ----------------
__global__ void k_count(const int* __restrict__ dst, int* __restrict__ cnt) {
    int e = blockIdx.x * 256 + threadIdx.x;
    atomicAdd(&cnt[dst[e]], 1);
}

__global__ void k_partial(const int* __restrict__ cnt, int* __restrict__ part) {
    __shared__ int sm[256];
    int t = threadIdx.x;
    sm[t] = cnt[blockIdx.x * 256 + t];
    __syncthreads();
    for (int s = 128; s > 0; s >>= 1) {
        if (t < s) sm[t] += sm[t + s];
        __syncthreads();
    }
    if (t == 0) part[blockIdx.x] = sm[0];
}

__global__ void k_scanpart(const int* __restrict__ part, int* __restrict__ pscan, int nb) {
    __shared__ int sm[512];
    int t = threadIdx.x;
    int v = (t < nb) ? part[t] : 0;
    sm[t] = v;
    __syncthreads();
    for (int s = 1; s < 512; s <<= 1) {
        int add = (t >= s) ? sm[t - s] : 0;
        __syncthreads();
        sm[t] += add;
        __syncthreads();
    }
    if (t < nb) pscan[t] = sm[t] - v;   // exclusive
}

// offsets + dinv fused (both need cnt[g])
__global__ void k_offsets(const int* __restrict__ cnt, const int* __restrict__ pscan,
                          int* __restrict__ offs, float* __restrict__ dinv) {
    __shared__ int sm[256];
    int t = threadIdx.x, g = blockIdx.x * 256 + t;
    int v = cnt[g];
    sm[t] = v;
    __syncthreads();
    for (int s = 1; s < 256; s <<= 1) {
        int add = (t >= s) ? sm[t - s] : 0;
        __syncthreads();
        sm[t] += add;
        __syncthreads();
    }
    offs[g] = pscan[blockIdx.x] + sm[t] - v;
    dinv[g] = rsqrtf((float)(v + 1));  // +1 self loop
}

__global__ void k_fill(const int* __restrict__ src, const int* __restrict__ dst,
                       const int* __restrict__ offs, int* __restrict__ fill,
                       const float* __restrict__ dinv,
                       int* __restrict__ csr, float* __restrict__ csrw) {
    int e = blockIdx.x * 256 + threadIdx.x;
    int d = dst[e];
    int s = src[e];
    int pos = offs[d] + atomicAdd(&fill[d], 1);
    csr[pos] = s;
    csrw[pos] = dinv[s];
}

// ---------------- weight transpose + fp16 hi/lo split, PACKED MFMA-fragment layout -------
// Packed layout per region: element index = ((ntile*(K/32) + kblk)*64 + lane)*8 + j
//   where col = ntile*16 + (lane&15), k = kblk*32 + (lane>>4)*8 + j.
// A wave's B-fragment load is then one contiguous 1KB transaction.
#define OFF_GCN 0                 // 5 x K=128 N=128
#define OFF_P0  81920             // combined mw0: K=128 N=512 (cols<256: top->Abuf, else bottom->Bbuf)
#define OFF_M1  147456            // mw1: K=256 N=128
#define OFF_M2  180224            // mw2: K=128 N=128
#define OFF_M3  196608            // mw3: K=128 N=64
#define OFF_M4  204800            // mw4: K=64  N=64
#define TS_TOTAL 208896

__global__ void k_tsplit_all(const float* __restrict__ gw, const float* __restrict__ mw0,
                             const float* __restrict__ mw1, const float* __restrict__ mw2,
                             const float* __restrict__ mw3, const float* __restrict__ mw4,
                             _Float16* __restrict__ hi, _Float16* __restrict__ lo) {
    int idx = blockIdx.x * 256 + threadIdx.x;
    const float* src;
    int K, N, rel;
    bool p0 = false;
    if (idx < OFF_P0) {
        int L = (idx - OFF_GCN) >> 14; rel = (idx - OFF_GCN) & 16383;
        src = gw + L * 16384; K = 128; N = 128;
    } else if (idx < OFF_M1) {
        rel = idx - OFF_P0; src = mw0; K = 128; N = 512; p0 = true;
    } else if (idx < OFF_M2) {
        rel = idx - OFF_M1;  src = mw1; K = 256; N = 128;
    } else if (idx < OFF_M3) {
        rel = idx - OFF_M2;  src = mw2; K = 128; N = 128;
    } else if (idx < OFF_M4) {
        rel = idx - OFF_M3;  src = mw3; K = 128; N = 64;
    } else {
        rel = idx - OFF_M4;  src = mw4; K = 64;  N = 64;
    }
    int kblks = K >> 5;
    int j = rel & 7;
    int lane = (rel >> 3) & 63;
    int t2 = rel >> 9;
    int kblk = t2 % kblks;
    int ntile = t2 / kblks;
    int col = ntile * 16 + (lane & 15);
    int k = kblk * 32 + ((lane >> 4) << 3) + j;
    float f;
    if (p0) {
        f = (col < 256) ? src[k * 256 + col] : src[(k + 128) * 256 + (col - 256)];
    } else {
        f = src[k * N + col];
    }
    _Float16 h = (_Float16)f;
    hi[idx] = h;
    lo[idx] = (_Float16)(f - (float)h);
}

// ---------------- split-fp16 MFMA GEMM ----------------
// B pre-packed in fragment order (hi/lo). 3-product Markidis split, fp32 accumulate.
// Block = 256 thr = 4 waves; wave owns 32 rows x NT_N*16 cols. No LDS.
// FUSEA: A row p comes from lrelu(FA[b,i,:] + FB[b,j,:]) (pair0 fused; mb0 folded into FA).
// P0SPLIT: epilogue routes cols<256 -> C(+bias), cols>=256 -> C2 (raw).
template <int NT_N, bool LEAKY, bool BIAS, bool P0SPLIT, bool FUSEA>
__launch_bounds__(256, 2)
__global__ void hgemm(const float* __restrict__ A,
                      const float* __restrict__ FA, const float* __restrict__ FB,
                      const _Float16* __restrict__ Bh, const _Float16* __restrict__ Bl,
                      const float* __restrict__ bias,
                      float* __restrict__ C, float* __restrict__ C2,
                      int N, int K) {
    const int KB = K >> 5;
    const int lane = threadIdx.x & 63;
    const int wid = threadIdx.x >> 6;
    const int lm = lane & 15, lq = lane >> 4;
    const int m0 = blockIdx.x * 128 + wid * 32;
    const int n0t = blockIdx.y * NT_N;

    const float* arow[2];
    const float* brow[2];
#pragma unroll
    for (int mt = 0; mt < 2; mt++) {
        int row = m0 + mt * 16 + lm;
        if (FUSEA) {
            int b = row / (NQ * NQ);
            int rr = row - b * (NQ * NQ);
            int i = rr / NQ;
            int j = rr - i * NQ;
            arow[mt] = FA + (size_t)(b * NQ + i) * 256;
            brow[mt] = FB + (size_t)(b * NQ + j) * 256;
        } else {
            arow[mt] = A + (size_t)row * K;
        }
    }

    floatx4 acc[2][NT_N];
#pragma unroll
    for (int mt = 0; mt < 2; mt++)
#pragma unroll
        for (int nt = 0; nt < NT_N; nt++) acc[mt][nt] = (floatx4)0.f;

    for (int kb = 0; kb < KB; kb++) {
        const int k0 = kb * 32 + lq * 8;
        half8 ahi[2], alo[2];
#pragma unroll
        for (int mt = 0; mt < 2; mt++) {
            floatx4 av0, av1;
            if (FUSEA) {
                floatx4 fa0 = *(const floatx4*)(arow[mt] + k0);
                floatx4 fa1 = *(const floatx4*)(arow[mt] + k0 + 4);
                floatx4 fb0 = *(const floatx4*)(brow[mt] + k0);
                floatx4 fb1 = *(const floatx4*)(brow[mt] + k0 + 4);
#pragma unroll
                for (int q = 0; q < 4; q++) {
                    av0[q] = lrelu(fa0[q] + fb0[q]);
                    av1[q] = lrelu(fa1[q] + fb1[q]);
                }
            } else {
                av0 = *(const floatx4*)(arow[mt] + k0);
                av1 = *(const floatx4*)(arow[mt] + k0 + 4);
            }
#pragma unroll
            for (int q = 0; q < 4; q++) {
                _Float16 h0 = (_Float16)av0[q];
                ahi[mt][q] = h0;
                alo[mt][q] = (_Float16)(av0[q] - (float)h0);
                _Float16 h1 = (_Float16)av1[q];
                ahi[mt][4 + q] = h1;
                alo[mt][4 + q] = (_Float16)(av1[q] - (float)h1);
            }
        }
#pragma unroll
        for (int nt = 0; nt < NT_N; nt++) {
            size_t boff = (((size_t)(n0t + nt) * KB + kb) * 64 + lane) * 8;
            half8 bhi = *(const half8*)(Bh + boff);
            half8 blo = *(const half8*)(Bl + boff);
#pragma unroll
            for (int mt = 0; mt < 2; mt++) {
                acc[mt][nt] = __builtin_amdgcn_mfma_f32_16x16x32_f16(ahi[mt], bhi, acc[mt][nt], 0, 0, 0);
                acc[mt][nt] = __builtin_amdgcn_mfma_f32_16x16x32_f16(ahi[mt], blo, acc[mt][nt], 0, 0, 0);
                acc[mt][nt] = __builtin_amdgcn_mfma_f32_16x16x32_f16(alo[mt], bhi, acc[mt][nt], 0, 0, 0);
            }
        }
    }

    // epilogue: C/D layout col=lane&15, row=(lane>>4)*4+reg
#pragma unroll
    for (int nt = 0; nt < NT_N; nt++) {
        int col = (n0t + nt) * 16 + lm;
        float bv = (BIAS || P0SPLIT) ? bias[col < 256 ? col : 0] : 0.f;
#pragma unroll
        for (int mt = 0; mt < 2; mt++) {
#pragma unroll
            for (int r = 0; r < 4; r++) {
                int row = m0 + mt * 16 + lq * 4 + r;
                float val = acc[mt][nt][r];
                if (P0SPLIT) {
                    if (col < 256) C[(size_t)row * 256 + col] = val + bv;
                    else C2[(size_t)row * 256 + col - 256] = val;
                } else {
                    if (BIAS) val += bv;
                    if (LEAKY) val = lrelu(val);
                    C[(size_t)row * N + col] = val;
                }
            }
        }
    }
}

// ---------------- GCN aggregation + bias + (leaky) + residual ----------------
// half-wave per node (32 lanes x float4 = 1 row); wave = 2 nodes -> 1KB per gather instr.
// clamp-masked unroll-4 keeps 4 gathers in flight without divergent branches.
__global__ void k_agg(const float* __restrict__ hw, const float* __restrict__ hold,
                      const int* __restrict__ csr, const float* __restrict__ csrw,
                      const int* __restrict__ offs, const int* __restrict__ cnt,
                      const float* __restrict__ dinv, const float* __restrict__ bias,
                      float* __restrict__ hnew, int leaky) {
    int tid = threadIdx.x;
    int sl = tid & 31;
    int node = blockIdx.x * 8 + (tid >> 5);
    float di = dinv[node];
    int off = offs[node], deg = cnt[node];
    float s2 = di * di;
    float4 v = ((const float4*)(hw + (size_t)node * FEAT))[sl];
    float ax = v.x * s2, ay = v.y * s2, az = v.z * s2, aw = v.w * s2;
    for (int e = 0; e < deg; e += 4) {
        int e0 = e, e1 = min(e + 1, deg - 1), e2 = min(e + 2, deg - 1), e3 = min(e + 3, deg - 1);
        int s0i = csr[off + e0], s1i = csr[off + e1], s2i = csr[off + e2], s3i = csr[off + e3];
        float w0 = csrw[off + e0] * di;
        float w1 = (e + 1 < deg) ? csrw[off + e1] * di : 0.f;
        float w2 = (e + 2 < deg) ? csrw[off + e2] * di : 0.f;
        float w3 = (e + 3 < deg) ? csrw[off + e3] * di : 0.f;
        float4 u0 = ((const float4*)(hw + (size_t)s0i * FEAT))[sl];
        float4 u1 = ((const float4*)(hw + (size_t)s1i * FEAT))[sl];
        float4 u2 = ((const float4*)(hw + (size_t)s2i * FEAT))[sl];
        float4 u3 = ((const float4*)(hw + (size_t)s3i * FEAT))[sl];
        ax += u0.x * w0 + u1.x * w1 + u2.x * w2 + u3.x * w3;
        ay += u0.y * w0 + u1.y * w1 + u2.y * w2 + u3.y * w3;
        az += u0.z * w0 + u1.z * w1 + u2.z * w2 + u3.z * w3;
        aw += u0.w * w0 + u1.w * w1 + u2.w * w2 + u3.w * w3;
    }
    float4 bv = ((const float4*)bias)[sl];
    ax += bv.x; ay += bv.y; az += bv.z; aw += bv.w;
    if (leaky) { ax = lrelu(ax); ay = lrelu(ay); az = lrelu(az); aw = lrelu(aw); }
    float4 ho = ((const float4*)(hold + (size_t)node * FEAT))[sl];
    ((float4*)(hnew + (size_t)node * FEAT))[sl] = make_float4(ax + ho.x, ay + ho.y, az + ho.z, aw + ho.w);
}

// ---------------- extract first-20 nodes per graph ----------------
__global__ void k_hq(const float* __restrict__ h, float* __restrict__ hq) {
    int t = blockIdx.x * 256 + threadIdx.x;
    int r = t >> 5, c4 = t & 31;
    int b = r / NQ, q = r % NQ;
    ((float4*)(hq + (size_t)r * FEAT))[c4] =
        ((const float4*)(h + (size_t)(b * NQ * NLAY + q) * FEAT))[c4];
}

// ---------------- last layer + symmetrize, one block per batch ----------------
__global__ void k_lastsym(const float* __restrict__ X4, const float* __restrict__ mw5,
                          const float* __restrict__ mb5, float* __restrict__ out) {
    __shared__ float w[64];
    __shared__ float sm[NQ * NQ];
    int t = threadIdx.x;
    if (t < 64) w[t] = mw5[t];
    __syncthreads();
    int b = blockIdx.x;
    for (int p = t; p < NQ * NQ; p += 256) {
        const float4* row = (const float4*)(X4 + (size_t)(b * NQ * NQ + p) * 64);
        float s = 0.f;
#pragma unroll
        for (int k4 = 0; k4 < 16; k4++) {
            float4 v = row[k4];
            s += v.x * w[k4 * 4] + v.y * w[k4 * 4 + 1] + v.z * w[k4 * 4 + 2] + v.w * w[k4 * 4 + 3];
        }
        sm[p] = s + mb5[0];
    }
    __syncthreads();
    for (int r = t; r < NQ * NQ; r += 256) {
        int i = r / NQ, j = r % NQ;
        out[(size_t)b * NQ * NQ + r] = 0.5f * (sm[r] + sm[j * NQ + i]);
    }
}

extern "C" void kernel_launch(void* const* d_in, const int* in_sizes, int n_in,
                              void* d_out, int out_size, void* d_ws, size_t ws_size,
                              hipStream_t stream) {
    const int* x = (const int*)d_in[0];
    const int* ei = (const int*)d_in[1];
    const int* e_src = ei;
    const int* e_dst = ei + NE;
    const float* emb = (const float*)d_in[2];
    const float* gw = (const float*)d_in[3];   // [5,128,128]
    const float* gb = (const float*)d_in[4];   // [5,128]
    const float* mw0 = (const float*)d_in[5];
    const float* mb0 = (const float*)d_in[6];
    const float* mw1 = (const float*)d_in[7];
    const float* mb1 = (const float*)d_in[8];
    const float* mw2 = (const float*)d_in[9];
    const float* mb2 = (const float*)d_in[10];
    const float* mw3 = (const float*)d_in[11];
    const float* mb3 = (const float*)d_in[12];
    const float* mw4 = (const float*)d_in[13];
    const float* mb4 = (const float*)d_in[14];
    const float* mw5 = (const float*)d_in[15];
    const float* mb5 = (const float*)d_in[16];
    float* out = (float*)d_out;

    float* wsf = (float*)d_ws;
    size_t o = 0;
    const size_t HSZ = (size_t)NN * FEAT;             // 16,711,680
    float* hA = wsf + o; o += HSZ;
    float* hw = wsf + o; o += HSZ;
    float* hB = wsf + o; o += HSZ;
    int* cnt  = (int*)(wsf + o); o += NN;
    int* fill = (int*)(wsf + o); o += NN;   // adjacent to cnt -> single memset
    int* offs = (int*)(wsf + o); o += NN;
    int* csr  = (int*)(wsf + o); o += NE;
    float* csrw = wsf + o; o += NE;
    float* dinv = wsf + o; o += NN;
    int* part  = (int*)(wsf + o); o += 512;
    int* pscan = (int*)(wsf + o); o += 512;
    float* hq = wsf + o; o += (size_t)BATCH * NQ * FEAT;     // 327,680
    float* Abuf = wsf + o; o += (size_t)BATCH * NQ * 256;    // 655,360
    float* Bbuf = wsf + o; o += (size_t)BATCH * NQ * 256;    // 655,360
    _Float16* bt_hi = (_Float16*)(wsf + o); o += (TS_TOTAL + 2) / 2;
    _Float16* bt_lo = (_Float16*)(wsf + o); o += (TS_TOTAL + 2) / 2;
    // aliases into freed h buffers (pair phase only)
    float* X1 = hw;                        // 51200*128
    float* X2 = hw + (size_t)NPAIR * 128;  // 51200*128
    float* X3 = hA;                        // 51200*64
    float* X4 = hA + (size_t)NPAIR * 64;   // 51200*64

    const int NB = NN / 256;  // 510

    // --- weight transpose+split+pack ---
    k_tsplit_all<<<TS_TOTAL / 256, 256, 0, stream>>>(gw, mw0, mw1, mw2, mw3, mw4, bt_hi, bt_lo);

    // --- CSR build ---
    hipMemsetAsync(cnt, 0, 2 * NN * sizeof(int), stream);  // cnt + fill
    k_count<<<NE / 256, 256, 0, stream>>>(e_dst, cnt);
    k_partial<<<NB, 256, 0, stream>>>(cnt, part);
    k_scanpart<<<1, 512, 0, stream>>>(part, pscan, NB);
    k_offsets<<<NB, 256, 0, stream>>>(cnt, pscan, offs, dinv);
    k_fill<<<NE / 256, 256, 0, stream>>>(e_src, e_dst, offs, fill, dinv, csr, csrw);

    // --- embedding ---
    k_embed<<<(NN * 32) / 256, 256, 0, stream>>>(x, emb, hA);

    // --- 5 GCN layers, ping-pong hA/hB ---
    float* hin = hA;
    float* hout = hB;
    for (int L = 0; L < 5; L++) {
        hgemm<8, false, false, false, false><<<dim3(NN / 128, 1), 256, 0, stream>>>(
            hin, nullptr, nullptr, bt_hi + OFF_GCN + L * 16384, bt_lo + OFF_GCN + L * 16384,
            nullptr, hw, nullptr, FEAT, FEAT);
        k_agg<<<NN / 8, 256, 0, stream>>>(hw, hin, csr, csrw, offs, cnt, dinv,
                                          gb + (size_t)L * FEAT, hout, L < 4 ? 1 : 0);
        float* t = hin; hin = hout; hout = t;
    }
    // final h in hin (== hB after 5 swaps); hA free

    // --- pair MLP ---
    k_hq<<<(BATCH * NQ * 32) / 256, 256, 0, stream>>>(hin, hq);
    // combined P0: Abuf = hq@mw0_top + mb0 ; Bbuf = hq@mw0_bot   (M=2560, K=128, N=512)
    hgemm<8, false, false, true, false><<<dim3(20, 4), 256, 0, stream>>>(
        hq, nullptr, nullptr, bt_hi + OFF_P0, bt_lo + OFF_P0, mb0, Abuf, Bbuf, 512, 128);
    // L1 with fused pair0: A[p,:] = lrelu(Abuf[b,i,:] + Bbuf[b,j,:]) ; [51200,256]@[256,128]
    hgemm<8, true, true, false, true><<<dim3(NPAIR / 128, 1), 256, 0, stream>>>(
        nullptr, Abuf, Bbuf, bt_hi + OFF_M1, bt_lo + OFF_M1, mb1, X1, nullptr, 128, 256);
    // L2: [51200,128] @ [128,128]
    hgemm<8, true, true, false, false><<<dim3(NPAIR / 128, 1), 256, 0, stream>>>(
        X1, nullptr, nullptr, bt_hi + OFF_M2, bt_lo + OFF_M2, mb2, X2, nullptr, 128, 128);
    // L3: [51200,128] @ [128,64]
    hgemm<4, true, true, false, false><<<dim3(NPAIR / 128, 1), 256, 0, stream>>>(
        X2, nullptr, nullptr, bt_hi + OFF_M3, bt_lo + OFF_M3, mb3, X3, nullptr, 64, 128);
    // L4: [51200,64] @ [64,64]
    hgemm<4, true, true, false, false><<<dim3(NPAIR / 128, 1), 256, 0, stream>>>(
        X3, nullptr, nullptr, bt_hi + OFF_M4, bt_lo + OFF_M4, mb4, X4, nullptr, 64, 64);
    // L5 + symmetrize (one block per batch)
    k_lastsym<<<BATCH, 256, 0, stream>>>(X4, mw5, mb5, out);
}